// Round 2
// baseline (514.763 us; speedup 1.0000x reference)
//
#include <hip/hip_runtime.h>
#include <hip/hip_bf16.h>

// Problem constants (from reference): B=16, N=4096 -> NTOK=65536, DIM=1024, T=8, E=64
#define NTOK  65536
#define DIM_  1024
#define NHEAD 8
#define EOUT  64
#define KBLK  32          // DIM_/32 k-steps of the 16x16x32 MFMA

typedef __bf16 bf16x8 __attribute__((ext_vector_type(8)));
typedef float  f32x4  __attribute__((ext_vector_type(4)));
typedef unsigned short u16x8 __attribute__((ext_vector_type(8)));

__device__ inline __bf16 cvt_bf16(float f) {
    __hip_bfloat16 h = __float2bfloat16(f);
    return __builtin_bit_cast(__bf16, h);
}

// ---------------------------------------------------------------------------
// Kernel 0: pack W [T, DIM, E] fp32 -> bf16 in exact MFMA B-fragment order.
// Wp flat index: (((t*KBLK + kb)*4 + et)*64 + lane)*8 + j
//   holds W[t][kb*32 + (lane>>4)*8 + j][et*16 + (lane&15)]
// ---------------------------------------------------------------------------
__global__ void pack_w(const float* __restrict__ W, unsigned short* __restrict__ Wp) {
    int x = blockIdx.x * blockDim.x + threadIdx.x;   // 8*32*4*64*8 = 524288 threads
    int j  = x & 7;
    int l  = (x >> 3) & 63;
    int et = (x >> 9) & 3;
    int kb = (x >> 11) & 31;
    int t  = x >> 16;
    int k = kb * 32 + (l >> 4) * 8 + j;
    int e = et * 16 + (l & 15);
    float v = W[((size_t)t * DIM_ + k) * EOUT + e];
    __hip_bfloat16 h = __float2bfloat16(v);
    Wp[x] = __builtin_bit_cast(unsigned short, h);
}

// ---------------------------------------------------------------------------
// Kernel 1: bucket tokens by head. Ballot-aggregated atomics: one atomicAdd
// per (wave, head) instead of per token.
// ---------------------------------------------------------------------------
__global__ void bucket_kernel(const int* __restrict__ idx,
                              int* __restrict__ cnt, int* __restrict__ list) {
    int i    = blockIdx.x * blockDim.x + threadIdx.x;   // exactly NTOK threads
    int lane = threadIdx.x & 63;
    int t = idx[i];
    #pragma unroll
    for (int h = 0; h < NHEAD; ++h) {
        unsigned long long m = __ballot(t == h);
        if (m) {
            int leader = __ffsll(m) - 1;
            int base = 0;
            if (lane == leader) base = atomicAdd(&cnt[h], __popcll(m));
            base = __shfl(base, leader, 64);
            if (t == h) {
                int rank = __popcll(m & ((1ull << lane) - 1ull));
                list[h * NTOK + base + rank] = i;
            }
        }
    }
}

// ---------------------------------------------------------------------------
// Kernel 2: gathered GEMM, exact grid. Each wave maps itself to (head, tile)
// via a prefix over cnt[8]; a tile is 32 gathered tokens x 64 outputs
// (two 16x16x32 MFMA row-tiles sharing B fragments). A rows gathered from
// emb (fp32 -> bf16 in regs); B fragments are 16B loads from L2-resident Wp.
// Max tiles = sum ceil(cnt/32) <= 2056; launch 516 blocks (2064 waves).
// ---------------------------------------------------------------------------
__global__ __launch_bounds__(256) void readout_gemm(
    const float* __restrict__ emb, const float* __restrict__ bias,
    const int* __restrict__ cnt, const int* __restrict__ list,
    const unsigned short* __restrict__ Wp, float* __restrict__ out)
{
    int wave = threadIdx.x >> 6;
    int lane = threadIdx.x & 63;
    int g = blockIdx.x * 4 + wave;   // global wave id = global tile id

    // Map wave -> (head, tile) via prefix of per-head tile counts
    int head = -1, tile = 0, count = 0, total = 0;
    #pragma unroll
    for (int h = 0; h < NHEAD; ++h) {
        int c = cnt[h];
        int th = (c + 31) >> 5;
        if (head < 0 && g < total + th) { head = h; tile = g - total; count = c; }
        total += th;
    }
    if (head < 0) return;

    int quad = lane >> 4, l16 = lane & 15;
    const int* mylist = list + head * NTOK;
    int mbase = tile * 32;

    // Gathered A rows for the two 16-row groups (clamp; stores masked later)
    int am0 = mbase + l16;        if (am0 > count - 1) am0 = count - 1;
    int am1 = mbase + 16 + l16;   if (am1 > count - 1) am1 = count - 1;
    int arow0 = mylist[am0];
    int arow1 = mylist[am1];
    const float* ap0 = emb + (size_t)arow0 * DIM_ + quad * 8;
    const float* ap1 = emb + (size_t)arow1 * DIM_ + quad * 8;

    // B fragment base: head block = KBLK*4*64*8 = 65536 ushorts
    const u16x8* bptr = reinterpret_cast<const u16x8*>(Wp + (size_t)head * 65536) + lane;

    f32x4 acc0[4] = {};
    f32x4 acc1[4] = {};

    #pragma unroll 2
    for (int kb = 0; kb < KBLK; ++kb) {
        const float4* p0 = reinterpret_cast<const float4*>(ap0 + kb * 32);
        const float4* p1 = reinterpret_cast<const float4*>(ap1 + kb * 32);
        float4 f0 = p0[0];
        float4 f1 = p0[1];
        float4 h0 = p1[0];
        float4 h1 = p1[1];
        u16x8 braw[4];
        #pragma unroll
        for (int et = 0; et < 4; ++et) braw[et] = bptr[(kb * 4 + et) * 64];

        bf16x8 a0, a1;
        a0[0] = cvt_bf16(f0.x); a0[1] = cvt_bf16(f0.y);
        a0[2] = cvt_bf16(f0.z); a0[3] = cvt_bf16(f0.w);
        a0[4] = cvt_bf16(f1.x); a0[5] = cvt_bf16(f1.y);
        a0[6] = cvt_bf16(f1.z); a0[7] = cvt_bf16(f1.w);
        a1[0] = cvt_bf16(h0.x); a1[1] = cvt_bf16(h0.y);
        a1[2] = cvt_bf16(h0.z); a1[3] = cvt_bf16(h0.w);
        a1[4] = cvt_bf16(h1.x); a1[5] = cvt_bf16(h1.y);
        a1[6] = cvt_bf16(h1.z); a1[7] = cvt_bf16(h1.w);

        #pragma unroll
        for (int et = 0; et < 4; ++et) {
            bf16x8 b = __builtin_bit_cast(bf16x8, braw[et]);
            acc0[et] = __builtin_amdgcn_mfma_f32_16x16x32_bf16(a0, b, acc0[et], 0, 0, 0);
            acc1[et] = __builtin_amdgcn_mfma_f32_16x16x32_bf16(a1, b, acc1[et], 0, 0, 0);
        }
    }

    // Epilogue: C layout col=lane&15, row=(lane>>4)*4+i. Scatter + bias.
    int tok0[4], tok1[4];
    #pragma unroll
    for (int i = 0; i < 4; ++i) {
        int m0 = mbase + quad * 4 + i;
        int m1 = mbase + 16 + quad * 4 + i;
        tok0[i] = (m0 < count) ? mylist[m0] : -1;
        tok1[i] = (m1 < count) ? mylist[m1] : -1;
    }
    #pragma unroll
    for (int et = 0; et < 4; ++et) {
        float bv = bias[head * EOUT + et * 16 + l16];
        #pragma unroll
        for (int i = 0; i < 4; ++i) {
            if (tok0[i] >= 0)
                out[(size_t)tok0[i] * EOUT + et * 16 + l16] = acc0[et][i] + bv;
            if (tok1[i] >= 0)
                out[(size_t)tok1[i] * EOUT + et * 16 + l16] = acc1[et][i] + bv;
        }
    }
}

// ---------------------------------------------------------------------------
// ws layout: [0,32)   cnt (8 ints, zeroed each call)
//            [1024, 1024+2MB)          per-head token lists
//            [1024+2MB, 1024+2MB+1MB)  packed bf16 W fragments
// total ~3.01 MB
// ---------------------------------------------------------------------------
extern "C" void kernel_launch(void* const* d_in, const int* in_sizes, int n_in,
                              void* d_out, int out_size, void* d_ws, size_t ws_size,
                              hipStream_t stream) {
    const float* emb  = (const float*)d_in[0];
    const int*   idx  = (const int*)d_in[1];
    const float* W    = (const float*)d_in[2];
    const float* bias = (const float*)d_in[3];
    float* out = (float*)d_out;

    char* ws = (char*)d_ws;
    int* cnt  = (int*)ws;
    int* list = (int*)(ws + 1024);
    unsigned short* Wp = (unsigned short*)(ws + 1024 + (size_t)NHEAD * NTOK * sizeof(int));

    hipMemsetAsync(cnt, 0, NHEAD * sizeof(int), stream);
    pack_w<<<(NHEAD * KBLK * 4 * 64 * 8) / 256, 256, 0, stream>>>(W, Wp);
    bucket_kernel<<<NTOK / 256, 256, 0, stream>>>(idx, cnt, list);
    // max tiles = sum_h ceil(cnt[h]/32) <= 2048 + 7; 516 blocks = 2064 waves
    readout_gemm<<<516, 256, 0, stream>>>(emb, bias, cnt, list, Wp, out);
}

// Round 3
// 448.265 us; speedup vs baseline: 1.1483x; 1.1483x over previous
//
#include <hip/hip_runtime.h>
#include <hip/hip_bf16.h>

// Problem constants (from reference): B=16, N=4096 -> NTOK=65536, DIM=1024, T=8, E=64
#define NTOK  65536
#define DIM_  1024
#define NHEAD 8
#define EOUT  64
#define KBLK  32          // DIM_/32 k-steps of the 16x16x32 MFMA
#define CNT_STRIDE 32     // pad each head counter to its own 128B line (atomic contention)

typedef __bf16 bf16x8 __attribute__((ext_vector_type(8)));
typedef float  f32x4  __attribute__((ext_vector_type(4)));
typedef unsigned short u16x8 __attribute__((ext_vector_type(8)));

__device__ inline __bf16 cvt_bf16(float f) {
    __hip_bfloat16 h = __float2bfloat16(f);
    return __builtin_bit_cast(__bf16, h);
}

// ---------------------------------------------------------------------------
// Kernel 0 (fused): pack W fp32 -> bf16 MFMA B-fragment order, AND bucket
// tokens by head (blocks 0..255 only). Counter for head h lives at
// cnt[h*CNT_STRIDE] so each head's atomics hit a distinct 128B L2 line.
// Wp flat index: (((t*KBLK + kb)*4 + et)*64 + lane)*8 + j
//   holds W[t][kb*32 + (lane>>4)*8 + j][et*16 + (lane&15)]
// ---------------------------------------------------------------------------
__global__ __launch_bounds__(256) void pack_and_bucket(
    const float* __restrict__ W, const int* __restrict__ idx,
    unsigned short* __restrict__ Wp, int* __restrict__ cnt,
    int* __restrict__ list)
{
    // ---- pack slice: 2048 blocks x 256 threads = 524288 elements ----
    int x = blockIdx.x * blockDim.x + threadIdx.x;
    {
        int j  = x & 7;
        int l  = (x >> 3) & 63;
        int et = (x >> 9) & 3;
        int kb = (x >> 11) & 31;
        int t  = x >> 16;
        int k = kb * 32 + (l >> 4) * 8 + j;
        int e = et * 16 + (l & 15);
        float v = W[((size_t)t * DIM_ + k) * EOUT + e];
        __hip_bfloat16 h = __float2bfloat16(v);
        Wp[x] = __builtin_bit_cast(unsigned short, h);
    }

    // ---- bucket slice: blocks 0..255 handle 256 tokens each ----
    if (blockIdx.x < NTOK / 256) {
        int i    = blockIdx.x * 256 + threadIdx.x;
        int lane = threadIdx.x & 63;
        int t = idx[i];
        #pragma unroll
        for (int h = 0; h < NHEAD; ++h) {
            unsigned long long m = __ballot(t == h);
            if (m) {
                int leader = __ffsll(m) - 1;
                int base = 0;
                if (lane == leader) base = atomicAdd(&cnt[h * CNT_STRIDE], __popcll(m));
                base = __shfl(base, leader, 64);
                if (t == h) {
                    int rank = __popcll(m & ((1ull << lane) - 1ull));
                    list[h * NTOK + base + rank] = i;
                }
            }
        }
    }
}

// ---------------------------------------------------------------------------
// Kernel 1: gathered GEMM, exact grid. Each wave maps itself to (head, tile)
// via a prefix over cnt; a tile is 32 gathered tokens x 64 outputs
// (two 16x16x32 MFMA row-tiles sharing B fragments). A rows gathered from
// emb (fp32 -> bf16 in regs); B fragments are 16B loads from L2-resident Wp.
// Max tiles = sum ceil(cnt/32) <= 2055; launch 514 blocks (2056 waves).
// ---------------------------------------------------------------------------
__global__ __launch_bounds__(256) void readout_gemm(
    const float* __restrict__ emb, const float* __restrict__ bias,
    const int* __restrict__ cnt, const int* __restrict__ list,
    const unsigned short* __restrict__ Wp, float* __restrict__ out)
{
    int wave = threadIdx.x >> 6;
    int lane = threadIdx.x & 63;
    int g = blockIdx.x * 4 + wave;   // global wave id = global tile id

    // Map wave -> (head, tile) via prefix of per-head tile counts
    int head = -1, tile = 0, count = 0, total = 0;
    #pragma unroll
    for (int h = 0; h < NHEAD; ++h) {
        int c = cnt[h * CNT_STRIDE];
        int th = (c + 31) >> 5;
        if (head < 0 && g < total + th) { head = h; tile = g - total; count = c; }
        total += th;
    }
    if (head < 0) return;

    int quad = lane >> 4, l16 = lane & 15;
    const int* mylist = list + head * NTOK;
    int mbase = tile * 32;

    // Gathered A rows for the two 16-row groups (clamp; stores masked later)
    int am0 = mbase + l16;        if (am0 > count - 1) am0 = count - 1;
    int am1 = mbase + 16 + l16;   if (am1 > count - 1) am1 = count - 1;
    int arow0 = mylist[am0];
    int arow1 = mylist[am1];
    const float* ap0 = emb + (size_t)arow0 * DIM_ + quad * 8;
    const float* ap1 = emb + (size_t)arow1 * DIM_ + quad * 8;

    // B fragment base: head block = KBLK*4*64*8 = 65536 ushorts
    const u16x8* bptr = reinterpret_cast<const u16x8*>(Wp + (size_t)head * 65536) + lane;

    f32x4 acc0[4] = {};
    f32x4 acc1[4] = {};

    #pragma unroll 2
    for (int kb = 0; kb < KBLK; ++kb) {
        const float4* p0 = reinterpret_cast<const float4*>(ap0 + kb * 32);
        const float4* p1 = reinterpret_cast<const float4*>(ap1 + kb * 32);
        float4 f0 = p0[0];
        float4 f1 = p0[1];
        float4 h0 = p1[0];
        float4 h1 = p1[1];
        u16x8 braw[4];
        #pragma unroll
        for (int et = 0; et < 4; ++et) braw[et] = bptr[(kb * 4 + et) * 64];

        bf16x8 a0, a1;
        a0[0] = cvt_bf16(f0.x); a0[1] = cvt_bf16(f0.y);
        a0[2] = cvt_bf16(f0.z); a0[3] = cvt_bf16(f0.w);
        a0[4] = cvt_bf16(f1.x); a0[5] = cvt_bf16(f1.y);
        a0[6] = cvt_bf16(f1.z); a0[7] = cvt_bf16(f1.w);
        a1[0] = cvt_bf16(h0.x); a1[1] = cvt_bf16(h0.y);
        a1[2] = cvt_bf16(h0.z); a1[3] = cvt_bf16(h0.w);
        a1[4] = cvt_bf16(h1.x); a1[5] = cvt_bf16(h1.y);
        a1[6] = cvt_bf16(h1.z); a1[7] = cvt_bf16(h1.w);

        #pragma unroll
        for (int et = 0; et < 4; ++et) {
            bf16x8 b = __builtin_bit_cast(bf16x8, braw[et]);
            acc0[et] = __builtin_amdgcn_mfma_f32_16x16x32_bf16(a0, b, acc0[et], 0, 0, 0);
            acc1[et] = __builtin_amdgcn_mfma_f32_16x16x32_bf16(a1, b, acc1[et], 0, 0, 0);
        }
    }

    // Epilogue: C layout col=lane&15, row=(lane>>4)*4+i. Scatter + bias.
    // Nontemporal: out is write-once, keep Wp/list resident in L2.
    int tok0[4], tok1[4];
    #pragma unroll
    for (int i = 0; i < 4; ++i) {
        int m0 = mbase + quad * 4 + i;
        int m1 = mbase + 16 + quad * 4 + i;
        tok0[i] = (m0 < count) ? mylist[m0] : -1;
        tok1[i] = (m1 < count) ? mylist[m1] : -1;
    }
    #pragma unroll
    for (int et = 0; et < 4; ++et) {
        float bv = bias[head * EOUT + et * 16 + l16];
        #pragma unroll
        for (int i = 0; i < 4; ++i) {
            if (tok0[i] >= 0)
                __builtin_nontemporal_store(acc0[et][i] + bv,
                    &out[(size_t)tok0[i] * EOUT + et * 16 + l16]);
            if (tok1[i] >= 0)
                __builtin_nontemporal_store(acc1[et][i] + bv,
                    &out[(size_t)tok1[i] * EOUT + et * 16 + l16]);
        }
    }
}

// ---------------------------------------------------------------------------
// ws layout: [0,1024)                  cnt (8 ints @ 128B stride, zeroed/call)
//            [1024, 1024+2MB)          per-head token lists
//            [1024+2MB, 1024+2MB+1MB)  packed bf16 W fragments
// total ~3.01 MB
// ---------------------------------------------------------------------------
extern "C" void kernel_launch(void* const* d_in, const int* in_sizes, int n_in,
                              void* d_out, int out_size, void* d_ws, size_t ws_size,
                              hipStream_t stream) {
    const float* emb  = (const float*)d_in[0];
    const int*   idx  = (const int*)d_in[1];
    const float* W    = (const float*)d_in[2];
    const float* bias = (const float*)d_in[3];
    float* out = (float*)d_out;

    char* ws = (char*)d_ws;
    int* cnt  = (int*)ws;
    int* list = (int*)(ws + 1024);
    unsigned short* Wp = (unsigned short*)(ws + 1024 + (size_t)NHEAD * NTOK * sizeof(int));

    hipMemsetAsync(cnt, 0, NHEAD * CNT_STRIDE * sizeof(int), stream);
    pack_and_bucket<<<(NHEAD * KBLK * 4 * 64 * 8) / 256, 256, 0, stream>>>(W, idx, Wp, cnt, list);
    // max tiles = sum_h ceil(cnt[h]/32) <= 2048 + 7; 514 blocks = 2056 waves
    readout_gemm<<<514, 256, 0, stream>>>(emb, bias, cnt, list, Wp, out);
}

// Round 5
// 414.985 us; speedup vs baseline: 1.2404x; 1.0802x over previous
//
#include <hip/hip_runtime.h>
#include <hip/hip_bf16.h>

// Problem constants (from reference): B=16, N=4096 -> NTOK=65536, DIM=1024, T=8, E=64
#define NTOK  65536
#define DIM_  1024
#define NHEAD 8
#define EOUT  64
#define KBLK  32          // DIM_/32 k-steps of the 16x16x32 MFMA
#define CNT_STRIDE 32     // pad each head counter to its own 128B line (atomic contention)

typedef __bf16 bf16x8 __attribute__((ext_vector_type(8)));
typedef float  f32x4  __attribute__((ext_vector_type(4)));
typedef unsigned short u16x8 __attribute__((ext_vector_type(8)));

__device__ inline __bf16 cvt_bf16(float f) {
    __hip_bfloat16 h = __float2bfloat16(f);
    return __builtin_bit_cast(__bf16, h);
}

// ---------------------------------------------------------------------------
// Kernel 0 (fused): pack W fp32 -> bf16 MFMA B-fragment order, AND bucket
// tokens by head (blocks 0..63 only; each wave owns 256 tokens and issues
// ONE atomic per head -> 2048 atomics total, 256 per padded line).
// Wp flat index: (((t*KBLK + kb)*4 + et)*64 + lane)*8 + j
//   holds W[t][kb*32 + (lane>>4)*8 + j][et*16 + (lane&15)]
// ---------------------------------------------------------------------------
__global__ __launch_bounds__(256) void pack_and_bucket(
    const float* __restrict__ W, const int* __restrict__ idx,
    unsigned short* __restrict__ Wp, int* __restrict__ cnt,
    int* __restrict__ list)
{
    // ---- pack slice: 2048 blocks x 256 threads = 524288 elements ----
    int x = blockIdx.x * blockDim.x + threadIdx.x;
    {
        int j  = x & 7;
        int l  = (x >> 3) & 63;
        int et = (x >> 9) & 3;
        int kb = (x >> 11) & 31;
        int t  = x >> 16;
        int k = kb * 32 + (l >> 4) * 8 + j;
        int e = et * 16 + (l & 15);
        float v = W[((size_t)t * DIM_ + k) * EOUT + e];
        __hip_bfloat16 h = __float2bfloat16(v);
        Wp[x] = __builtin_bit_cast(unsigned short, h);
    }

    // ---- bucket slice: blocks 0..63, wave w owns tokens [gw*256, gw*256+256) ----
    if (blockIdx.x < NTOK / 1024) {
        int wave = threadIdx.x >> 6;
        int lane = threadIdx.x & 63;
        int gw   = blockIdx.x * 4 + wave;        // 256 waves total
        int tbase = gw * 256;
        int t[4];
        #pragma unroll
        for (int c = 0; c < 4; ++c) t[c] = idx[tbase + c * 64 + lane];

        #pragma unroll
        for (int h = 0; h < NHEAD; ++h) {
            unsigned long long m[4];
            int nh = 0;
            #pragma unroll
            for (int c = 0; c < 4; ++c) {
                m[c] = __ballot(t[c] == h);
                nh += __popcll(m[c]);
            }
            int base = 0;
            if (lane == 0 && nh) base = atomicAdd(&cnt[h * CNT_STRIDE], nh);
            base = __shfl(base, 0, 64);
            int pre = 0;
            #pragma unroll
            for (int c = 0; c < 4; ++c) {
                if (t[c] == h) {
                    int rank = __popcll(m[c] & ((1ull << lane) - 1ull));
                    list[h * NTOK + base + pre + rank] = tbase + c * 64 + lane;
                }
                pre += __popcll(m[c]);
            }
        }
    }
}

// ---------------------------------------------------------------------------
// Kernel 1: gathered GEMM, exact grid. Each wave maps itself to (head, tile)
// via a prefix over cnt; a tile is 32 gathered tokens x 64 outputs
// (two 16x16x32 MFMA row-tiles sharing B fragments). A rows gathered from
// emb with NONTEMPORAL fp32 loads (emb streams once; keep Wp/list in L2),
// cvt->bf16 in regs; B fragments are 16B loads from L2-resident Wp.
// Max tiles = sum ceil(cnt/32) <= 2055; launch 514 blocks (2056 waves).
// ---------------------------------------------------------------------------
__global__ __launch_bounds__(256) void readout_gemm(
    const float* __restrict__ emb, const float* __restrict__ bias,
    const int* __restrict__ cnt, const int* __restrict__ list,
    const unsigned short* __restrict__ Wp, float* __restrict__ out)
{
    int wave = threadIdx.x >> 6;
    int lane = threadIdx.x & 63;
    int g = blockIdx.x * 4 + wave;   // global wave id = global tile id

    // Map wave -> (head, tile) via prefix of per-head tile counts
    int head = -1, tile = 0, count = 0, total = 0;
    #pragma unroll
    for (int h = 0; h < NHEAD; ++h) {
        int c = cnt[h * CNT_STRIDE];
        int th = (c + 31) >> 5;
        if (head < 0 && g < total + th) { head = h; tile = g - total; count = c; }
        total += th;
    }
    if (head < 0) return;

    int quad = lane >> 4, l16 = lane & 15;
    const int* mylist = list + head * NTOK;
    int mbase = tile * 32;

    // Gathered A rows for the two 16-row groups (clamp; stores masked later)
    int am0 = mbase + l16;        if (am0 > count - 1) am0 = count - 1;
    int am1 = mbase + 16 + l16;   if (am1 > count - 1) am1 = count - 1;
    int arow0 = mylist[am0];
    int arow1 = mylist[am1];
    const f32x4* ap0 = reinterpret_cast<const f32x4*>(emb + (size_t)arow0 * DIM_ + quad * 8);
    const f32x4* ap1 = reinterpret_cast<const f32x4*>(emb + (size_t)arow1 * DIM_ + quad * 8);

    // B fragment base: head block = KBLK*4*64*8 = 65536 ushorts
    const u16x8* bptr = reinterpret_cast<const u16x8*>(Wp + (size_t)head * 65536) + lane;

    f32x4 acc0[4] = {};
    f32x4 acc1[4] = {};

    #pragma unroll 2
    for (int kb = 0; kb < KBLK; ++kb) {
        // kb*32 floats = kb*8 f32x4 elements
        f32x4 f0 = __builtin_nontemporal_load(ap0 + kb * 8);
        f32x4 f1 = __builtin_nontemporal_load(ap0 + kb * 8 + 1);
        f32x4 h0 = __builtin_nontemporal_load(ap1 + kb * 8);
        f32x4 h1 = __builtin_nontemporal_load(ap1 + kb * 8 + 1);
        u16x8 braw[4];
        #pragma unroll
        for (int et = 0; et < 4; ++et) braw[et] = bptr[(kb * 4 + et) * 64];

        bf16x8 a0, a1;
        #pragma unroll
        for (int j = 0; j < 4; ++j) {
            a0[j]     = cvt_bf16(f0[j]);
            a0[j + 4] = cvt_bf16(f1[j]);
            a1[j]     = cvt_bf16(h0[j]);
            a1[j + 4] = cvt_bf16(h1[j]);
        }

        #pragma unroll
        for (int et = 0; et < 4; ++et) {
            bf16x8 b = __builtin_bit_cast(bf16x8, braw[et]);
            acc0[et] = __builtin_amdgcn_mfma_f32_16x16x32_bf16(a0, b, acc0[et], 0, 0, 0);
            acc1[et] = __builtin_amdgcn_mfma_f32_16x16x32_bf16(a1, b, acc1[et], 0, 0, 0);
        }
    }

    // Epilogue: C layout col=lane&15, row=(lane>>4)*4+i. Scatter + bias.
    // Nontemporal: out is write-once, keep Wp/list resident in L2.
    int tok0[4], tok1[4];
    #pragma unroll
    for (int i = 0; i < 4; ++i) {
        int m0 = mbase + quad * 4 + i;
        int m1 = mbase + 16 + quad * 4 + i;
        tok0[i] = (m0 < count) ? mylist[m0] : -1;
        tok1[i] = (m1 < count) ? mylist[m1] : -1;
    }
    #pragma unroll
    for (int et = 0; et < 4; ++et) {
        float bv = bias[head * EOUT + et * 16 + l16];
        #pragma unroll
        for (int i = 0; i < 4; ++i) {
            if (tok0[i] >= 0)
                __builtin_nontemporal_store(acc0[et][i] + bv,
                    &out[(size_t)tok0[i] * EOUT + et * 16 + l16]);
            if (tok1[i] >= 0)
                __builtin_nontemporal_store(acc1[et][i] + bv,
                    &out[(size_t)tok1[i] * EOUT + et * 16 + l16]);
        }
    }
}

// ---------------------------------------------------------------------------
// ws layout: [0,1024)                  cnt (8 ints @ 128B stride, zeroed/call)
//            [1024, 1024+2MB)          per-head token lists
//            [1024+2MB, 1024+2MB+1MB)  packed bf16 W fragments
// total ~3.01 MB
// ---------------------------------------------------------------------------
extern "C" void kernel_launch(void* const* d_in, const int* in_sizes, int n_in,
                              void* d_out, int out_size, void* d_ws, size_t ws_size,
                              hipStream_t stream) {
    const float* emb  = (const float*)d_in[0];
    const int*   idx  = (const int*)d_in[1];
    const float* W    = (const float*)d_in[2];
    const float* bias = (const float*)d_in[3];
    float* out = (float*)d_out;

    char* ws = (char*)d_ws;
    int* cnt  = (int*)ws;
    int* list = (int*)(ws + 1024);
    unsigned short* Wp = (unsigned short*)(ws + 1024 + (size_t)NHEAD * NTOK * sizeof(int));

    (void)hipMemsetAsync(cnt, 0, NHEAD * CNT_STRIDE * sizeof(int), stream);
    pack_and_bucket<<<(NHEAD * KBLK * 4 * 64 * 8) / 256, 256, 0, stream>>>(W, idx, Wp, cnt, list);
    // max tiles = sum_h ceil(cnt[h]/32) <= 2048 + 7; 514 blocks = 2056 waves
    readout_gemm<<<514, 256, 0, stream>>>(emb, bias, cnt, list, Wp, out);
}